// Round 13
// baseline (1078.343 us; speedup 1.0000x reference)
//
#include <hip/hip_runtime.h>

#define HID 128

typedef __attribute__((ext_vector_type(8))) short bf16x8;
typedef __attribute__((ext_vector_type(4))) float f32x4;
typedef __attribute__((ext_vector_type(4))) unsigned short u16x4;

__device__ __forceinline__ unsigned short f2bf(float f) {
  union { float f; unsigned u; } v; v.f = f;
  return (unsigned short)((v.u + 0x7FFFu + ((v.u >> 16) & 1u)) >> 16);
}
__device__ __forceinline__ float bf2f(unsigned short h) {
  union { unsigned u; float f; } v; v.u = ((unsigned)h) << 16; return v.f;
}
__device__ __forceinline__ float bf2f_lo(unsigned u) {
  union { unsigned u; float f; } v; v.u = u << 16; return v.f;
}
__device__ __forceinline__ float bf2f_hi(unsigned u) {
  union { unsigned u; float f; } v; v.u = u & 0xffff0000u; return v.f;
}

// Permuted bf16 layout: storage position p holds natural column
// c(p) = (p&7)*16 + (p>>3). Used for xb/hb/msgs/xf in the hoisted path.

// ---------------------------------------------------------------------------
// Register-blocked MFMA GEMM, no LDS. Block=256thr=4 waves; wave = 32 rows.
// ---------------------------------------------------------------------------
template<bool SRCF32, bool BIAS, bool OUTBF16>
__global__ __launch_bounds__(256, 3) void gemm_node_kernel(
    const void* __restrict__ Xv, const unsigned short* __restrict__ Wt,
    const float* __restrict__ bias, float* __restrict__ Yf,
    unsigned short* __restrict__ Yb, int nrows)
{
  const int tid  = threadIdx.x;
  const int lane = tid & 63;
  const int wave = tid >> 6;
  const int lr = lane & 15;
  const int lg = lane >> 4;
  const long row0 = (long)blockIdx.x * 128 + wave * 32;

  bf16x8 A[2][4];
  #pragma unroll
  for (int rt = 0; rt < 2; ++rt) {
    long R = row0 + rt * 16 + lr;
    if (R >= nrows) R = nrows - 1;
    if (SRCF32) {
      const float* xp = (const float*)Xv + R * HID;
      #pragma unroll
      for (int ks = 0; ks < 4; ++ks) {
        float4 lo = *(const float4*)(xp + ks * 32 + lg * 8);
        float4 hi = *(const float4*)(xp + ks * 32 + lg * 8 + 4);
        bf16x8 a;
        a[0] = (short)f2bf(lo.x); a[1] = (short)f2bf(lo.y);
        a[2] = (short)f2bf(lo.z); a[3] = (short)f2bf(lo.w);
        a[4] = (short)f2bf(hi.x); a[5] = (short)f2bf(hi.y);
        a[6] = (short)f2bf(hi.z); a[7] = (short)f2bf(hi.w);
        A[rt][ks] = a;
      }
    } else {
      const unsigned short* xp = (const unsigned short*)Xv + R * HID;
      #pragma unroll
      for (int ks = 0; ks < 4; ++ks)
        A[rt][ks] = *(const bf16x8*)(xp + ks * 32 + lg * 8);
    }
  }

  f32x4 acc[2][8];
  #pragma unroll
  for (int rt = 0; rt < 2; ++rt)
    #pragma unroll
    for (int ct = 0; ct < 8; ++ct)
      acc[rt][ct] = (f32x4){0.f, 0.f, 0.f, 0.f};

  #pragma unroll
  for (int ks = 0; ks < 4; ++ks) {
    bf16x8 Bf[8];
    #pragma unroll
    for (int ct = 0; ct < 8; ++ct)
      Bf[ct] = *(const bf16x8*)(Wt + (ct * 16 + lr) * HID + ks * 32 + lg * 8);
    #pragma unroll
    for (int rt = 0; rt < 2; ++rt)
      #pragma unroll
      for (int ct = 0; ct < 8; ++ct)
        acc[rt][ct] = __builtin_amdgcn_mfma_f32_16x16x32_bf16(
            A[rt][ks], Bf[ct], acc[rt][ct], 0, 0, 0);
  }

  #pragma unroll
  for (int rt = 0; rt < 2; ++rt) {
    #pragma unroll
    for (int r = 0; r < 4; ++r) {
      long e = row0 + rt * 16 + lg * 4 + r;
      if (e < nrows) {
        if (OUTBF16) {
          bf16x8 o;
          #pragma unroll
          for (int ct = 0; ct < 8; ++ct) {
            float v = acc[rt][ct][r];
            if (BIAS) v += bias[ct * 16 + lr];
            o[ct] = (short)f2bf(v);
          }
          *(bf16x8*)(Yb + e * HID + lr * 8) = o;   // permuted, contiguous
        } else {
          #pragma unroll
          for (int ct = 0; ct < 8; ++ct) {
            int col = ct * 16 + lr;
            float v = acc[rt][ct][r];
            if (BIAS) v += bias[col];
            Yf[e * HID + col] = v;                  // natural
          }
        }
      }
    }
  }
}

// ---------------------------------------------------------------------------
// Pre-gather: EAs[slot] = bf16(EA[perm[slot]]). Random read ONCE with
// massive memory-level parallelism (25.6M threads, 1 float4 each) — this
// is the fastest observed form of the random 512B-granule read (~4 TB/s).
// ---------------------------------------------------------------------------
__global__ __launch_bounds__(256) void gather_ea_kernel(
    const float* __restrict__ EA, const int* __restrict__ perm,
    unsigned short* __restrict__ EAs, int nE)
{
  long idx = (long)blockIdx.x * 256 + threadIdx.x;
  long slot = idx >> 5;
  if (slot >= nE) return;
  int part = (int)(idx & 31);
  const float* xp = EA + (long)perm[slot] * HID + part * 4;
  float4 v = *(const float4*)xp;
  u16x4 o;
  o[0] = f2bf(v.x); o[1] = f2bf(v.y); o[2] = f2bf(v.z); o[3] = f2bf(v.w);
  *(u16x4*)(EAs + slot * HID + part * 4) = o;
}

// ---------------------------------------------------------------------------
// Tri edge GEMM v3: A = EAs[slot] (bf16, SEQUENTIAL stream, per-lane 16B
// loads); for each of the 3 gcn_ew weights: B-stream from L2 + 64 MFMA +
// write msgs_w (bf16, permuted, dst-sorted). Pure streaming kernel.
// ---------------------------------------------------------------------------
__global__ __launch_bounds__(256, 3) void tri_edge_gemm_kernel(
    const unsigned short* __restrict__ EAs,
    const unsigned short* __restrict__ Wt,   // 3 matrices, stride 16384
    unsigned short* __restrict__ msgs, int nE)  // 3 buffers, stride nE*HID
{
  const int tid  = threadIdx.x;
  const int lane = tid & 63;
  const int wave = tid >> 6;
  const int lr = lane & 15;
  const int lg = lane >> 4;
  const long row0 = (long)blockIdx.x * 128 + wave * 32;

  bf16x8 A[2][4];
  #pragma unroll
  for (int rt = 0; rt < 2; ++rt) {
    const unsigned short* xp = EAs + (row0 + rt * 16 + lr) * HID;
    #pragma unroll
    for (int ks = 0; ks < 4; ++ks)
      A[rt][ks] = *(const bf16x8*)(xp + ks * 32 + lg * 8);
  }

  #pragma unroll 1
  for (int w = 0; w < 3; ++w) {
    const unsigned short* Wp = Wt + (size_t)w * 16384;
    unsigned short* Mp = msgs + (size_t)w * nE * HID;

    f32x4 acc[2][8];
    #pragma unroll
    for (int rt = 0; rt < 2; ++rt)
      #pragma unroll
      for (int ct = 0; ct < 8; ++ct)
        acc[rt][ct] = (f32x4){0.f, 0.f, 0.f, 0.f};

    #pragma unroll
    for (int ks = 0; ks < 4; ++ks) {
      bf16x8 Bf[8];
      #pragma unroll
      for (int ct = 0; ct < 8; ++ct)
        Bf[ct] = *(const bf16x8*)(Wp + (ct * 16 + lr) * HID + ks * 32 + lg * 8);
      #pragma unroll
      for (int rt = 0; rt < 2; ++rt)
        #pragma unroll
        for (int ct = 0; ct < 8; ++ct)
          acc[rt][ct] = __builtin_amdgcn_mfma_f32_16x16x32_bf16(
              A[rt][ks], Bf[ct], acc[rt][ct], 0, 0, 0);
    }

    #pragma unroll
    for (int rt = 0; rt < 2; ++rt) {
      #pragma unroll
      for (int r = 0; r < 4; ++r) {
        long e = row0 + rt * 16 + lg * 4 + r;
        bf16x8 o;
        #pragma unroll
        for (int ct = 0; ct < 8; ++ct) o[ct] = (short)f2bf(acc[rt][ct][r]);
        *(bf16x8*)(Mp + e * HID + lr * 8) = o;
      }
    }
  }
}

// ---------------------------------------------------------------------------
// Fused segmented-reduce + LN, wave-autonomous: each WAVE owns 8 consecutive
// dsts; lane owns a column PAIR (uint loads of msgs/Hb, 256B/row coalesced);
// dual 2-slot unroll; LN via 64-lane shfl only (no LDS, no syncthreads).
// ---------------------------------------------------------------------------
__global__ __launch_bounds__(256) void seg_ln_kernel(
    const unsigned short* __restrict__ msgs, const unsigned short* __restrict__ Hb,
    const int* __restrict__ ssrc, const int* __restrict__ segend,
    const float* __restrict__ b, const float* __restrict__ lnS,
    const float* __restrict__ lnB, const float* res,
    float* __restrict__ xf, unsigned short* __restrict__ xb)
{
  const int lane = threadIdx.x & 63;
  const int wave = threadIdx.x >> 6;
  const int dbase = blockIdx.x * 32 + wave * 8;
  const int c = lane * 2;              // permuted column pair

  const float2 bb = *(const float2*)&b[c];
  const float2 sc = *(const float2*)&lnS[c];
  const float2 sb = *(const float2*)&lnB[c];

  int p = (dbase == 0) ? 0 : segend[dbase - 1];
  #pragma unroll 1
  for (int j = 0; j < 8; ++j) {
    const long node = dbase + j;
    const int end = segend[node];
    float a00 = 0.f, a01 = 0.f, a10 = 0.f, a11 = 0.f;
    int q = p;
    for (; q + 1 < end; q += 2) {
      int s0 = ssrc[q];
      int s1 = ssrc[q + 1];
      unsigned m0 = *(const unsigned*)(msgs + (long)q * HID + c);
      unsigned h0 = *(const unsigned*)(Hb + (long)s0 * HID + c);
      unsigned m1 = *(const unsigned*)(msgs + (long)(q + 1) * HID + c);
      unsigned h1 = *(const unsigned*)(Hb + (long)s1 * HID + c);
      a00 += bf2f_lo(m0) * bf2f_lo(h0);
      a01 += bf2f_hi(m0) * bf2f_hi(h0);
      a10 += bf2f_lo(m1) * bf2f_lo(h1);
      a11 += bf2f_hi(m1) * bf2f_hi(h1);
    }
    if (q < end) {
      int s = ssrc[q];
      unsigned m = *(const unsigned*)(msgs + (long)q * HID + c);
      unsigned h = *(const unsigned*)(Hb + (long)s * HID + c);
      a00 += bf2f_lo(m) * bf2f_lo(h);
      a01 += bf2f_hi(m) * bf2f_hi(h);
    }
    p = end;

    float v0 = fmaxf(a00 + a10 + bb.x, 0.f);
    float v1 = fmaxf(a01 + a11 + bb.y, 0.f);
    if (res != nullptr) {
      float2 rr = *(const float2*)&res[node * HID + c];
      v0 += rr.x; v1 += rr.y;
    }
    float s = v0 + v1, qq = v0 * v0 + v1 * v1;
    #pragma unroll
    for (int off = 32; off >= 1; off >>= 1) {
      s  += __shfl_xor(s, off);
      qq += __shfl_xor(qq, off);
    }
    float mean = s * (1.f / 128.f);
    float var = qq * (1.f / 128.f) - mean * mean;
    float rstd = rsqrtf(var + 1e-5f);
    float o0 = (v0 - mean) * rstd * sc.x + sb.x;
    float o1 = (v1 - mean) * rstd * sc.y + sb.y;
    *(float2*)&xf[node * HID + c] = make_float2(o0, o1);
    unsigned pk = (unsigned)f2bf(o0) | ((unsigned)f2bf(o1) << 16);
    *(unsigned*)&xb[node * HID + c] = pk;
  }
}

// ---------------------------------------------------------------------------
// Fallback fused edge kernel (ws too small): EA[perm] fp32 A-load, atomics
// into NATURAL agg (lane-major contiguous lines), permuted bf16 Hb gather.
// ---------------------------------------------------------------------------
__global__ __launch_bounds__(256, 3) void gemm_edge_fb_kernel(
    const float* __restrict__ EA, const int* __restrict__ perm,
    const unsigned short* __restrict__ Wt, const unsigned short* __restrict__ Hb,
    const int* __restrict__ ssrc, const int* __restrict__ sdst,
    float* __restrict__ agg, int nE)
{
  const int tid  = threadIdx.x;
  const int lane = tid & 63;
  const int wave = tid >> 6;
  const int lr = lane & 15;
  const int lg = lane >> 4;
  const long row0 = (long)blockIdx.x * 128 + wave * 32;

  bf16x8 A[2][4];
  #pragma unroll
  for (int rt = 0; rt < 2; ++rt) {
    long R = row0 + rt * 16 + lr;
    const float* xp = EA + (long)perm[R] * HID;
    #pragma unroll
    for (int ks = 0; ks < 4; ++ks) {
      float4 lo = *(const float4*)(xp + ks * 32 + lg * 8);
      float4 hi = *(const float4*)(xp + ks * 32 + lg * 8 + 4);
      bf16x8 a;
      a[0] = (short)f2bf(lo.x); a[1] = (short)f2bf(lo.y);
      a[2] = (short)f2bf(lo.z); a[3] = (short)f2bf(lo.w);
      a[4] = (short)f2bf(hi.x); a[5] = (short)f2bf(hi.y);
      a[6] = (short)f2bf(hi.z); a[7] = (short)f2bf(hi.w);
      A[rt][ks] = a;
    }
  }

  f32x4 acc[2][8];
  #pragma unroll
  for (int rt = 0; rt < 2; ++rt)
    #pragma unroll
    for (int ct = 0; ct < 8; ++ct)
      acc[rt][ct] = (f32x4){0.f, 0.f, 0.f, 0.f};

  #pragma unroll
  for (int ks = 0; ks < 4; ++ks) {
    bf16x8 Bf[8];
    #pragma unroll
    for (int ct = 0; ct < 8; ++ct)
      Bf[ct] = *(const bf16x8*)(Wt + (ct * 16 + lr) * HID + ks * 32 + lg * 8);
    #pragma unroll
    for (int rt = 0; rt < 2; ++rt)
      #pragma unroll
      for (int ct = 0; ct < 8; ++ct)
        acc[rt][ct] = __builtin_amdgcn_mfma_f32_16x16x32_bf16(
            A[rt][ks], Bf[ct], acc[rt][ct], 0, 0, 0);
  }

  #pragma unroll
  for (int rt = 0; rt < 2; ++rt) {
    const long base = row0 + rt * 16 + lg * 4;
    int4 sv = *(const int4*)(ssrc + base);
    int4 dv = *(const int4*)(sdst + base);
    bf16x8 hv0 = *(const bf16x8*)(Hb + (long)sv.x * HID + lr * 8);
    bf16x8 hv1 = *(const bf16x8*)(Hb + (long)sv.y * HID + lr * 8);
    bf16x8 hv2 = *(const bf16x8*)(Hb + (long)sv.z * HID + lr * 8);
    bf16x8 hv3 = *(const bf16x8*)(Hb + (long)sv.w * HID + lr * 8);

    float am[8];
    #pragma unroll
    for (int ct = 0; ct < 8; ++ct)
      am[ct] = acc[rt][ct][0] * bf2f((unsigned short)hv0[ct]);
    int dprev = dv.x;
    {
      bool same = (dv.y == dprev);
      if (!same) {
        float* ap = agg + (long)dprev * HID + lr;
        #pragma unroll
        for (int ct = 0; ct < 8; ++ct) atomicAdd(ap + ct * 16, am[ct]);
      }
      #pragma unroll
      for (int ct = 0; ct < 8; ++ct) {
        float m = acc[rt][ct][1] * bf2f((unsigned short)hv1[ct]);
        am[ct] = same ? am[ct] + m : m;
      }
      dprev = dv.y;
    }
    {
      bool same = (dv.z == dprev);
      if (!same) {
        float* ap = agg + (long)dprev * HID + lr;
        #pragma unroll
        for (int ct = 0; ct < 8; ++ct) atomicAdd(ap + ct * 16, am[ct]);
      }
      #pragma unroll
      for (int ct = 0; ct < 8; ++ct) {
        float m = acc[rt][ct][2] * bf2f((unsigned short)hv2[ct]);
        am[ct] = same ? am[ct] + m : m;
      }
      dprev = dv.z;
    }
    {
      bool same = (dv.w == dprev);
      if (!same) {
        float* ap = agg + (long)dprev * HID + lr;
        #pragma unroll
        for (int ct = 0; ct < 8; ++ct) atomicAdd(ap + ct * 16, am[ct]);
      }
      #pragma unroll
      for (int ct = 0; ct < 8; ++ct) {
        float m = acc[rt][ct][3] * bf2f((unsigned short)hv3[ct]);
        am[ct] = same ? am[ct] + m : m;
      }
      dprev = dv.w;
    }
    float* ap = agg + (long)dprev * HID + lr;
    #pragma unroll
    for (int ct = 0; ct < 8; ++ct) atomicAdd(ap + ct * 16, am[ct]);
  }
}

// ---------------------------------------------------------------------------
// Counting sort of edges by dst. After scatter, curs[d] = segment END.
// ---------------------------------------------------------------------------
__global__ void hist_kernel(const int* __restrict__ dst, int nE,
                            int* __restrict__ hist)
{
  int i = blockIdx.x * 256 + threadIdx.x;
  if (i < nE) atomicAdd(&hist[dst[i]], 1);
}

__global__ __launch_bounds__(256) void scan1_kernel(
    const int* __restrict__ hist, int n, int* __restrict__ partial)
{
  __shared__ int buf[256];
  int t = threadIdx.x;
  int i = blockIdx.x * 256 + t;
  buf[t] = (i < n) ? hist[i] : 0;
  __syncthreads();
  #pragma unroll
  for (int off = 128; off >= 1; off >>= 1) {
    if (t < off) buf[t] += buf[t + off];
    __syncthreads();
  }
  if (t == 0) partial[blockIdx.x] = buf[0];
}

__global__ __launch_bounds__(512) void scan2_kernel(int* __restrict__ partial,
                                                    int nb)
{
  __shared__ int buf[512];
  int t = threadIdx.x;
  buf[t] = (t < nb) ? partial[t] : 0;
  __syncthreads();
  for (int off = 1; off < 512; off <<= 1) {
    int v = (t >= off) ? buf[t - off] : 0;
    __syncthreads();
    buf[t] += v;
    __syncthreads();
  }
  if (t < nb) partial[t] = (t == 0) ? 0 : buf[t - 1];
}

__global__ __launch_bounds__(256) void scan3_kernel(
    const int* __restrict__ hist, const int* __restrict__ partial,
    int* __restrict__ cursor, int n)
{
  __shared__ int buf[256];
  int t = threadIdx.x;
  int i = blockIdx.x * 256 + t;
  int v = (i < n) ? hist[i] : 0;
  buf[t] = v;
  __syncthreads();
  for (int off = 1; off < 256; off <<= 1) {
    int w = (t >= off) ? buf[t - off] : 0;
    __syncthreads();
    buf[t] += w;
    __syncthreads();
  }
  if (i < n) cursor[i] = partial[blockIdx.x] + buf[t] - v;
}

__global__ void scatter_kernel(const int* __restrict__ src,
                               const int* __restrict__ dst, int nE,
                               int* __restrict__ cursor,
                               int* __restrict__ perm,
                               int* __restrict__ ssrc, int* __restrict__ sdst)
{
  int e = blockIdx.x * 256 + threadIdx.x;
  if (e < nE) {
    int d = dst[e];
    int pos = atomicAdd(&cursor[d], 1);
    perm[pos] = e;
    ssrc[pos] = src[e];
    sdst[pos] = d;
  }
}

// ---------------------------------------------------------------------------
// Weight prep: wt[m][n][k'] = bf16(W_m[key][n]); key = c(k') for matrices
// whose A-input is permuted (gcn_w m=1..3, opw m=7), else k'.
// ---------------------------------------------------------------------------
__global__ __launch_bounds__(256) void prep_w_kernel(
    const float* __restrict__ ipw, const float* __restrict__ gw,
    const float* __restrict__ gew, const float* __restrict__ opw,
    unsigned short* __restrict__ wt)
{
  int idx = blockIdx.x * 1024 + threadIdx.x * 4;
  #pragma unroll
  for (int t = 0; t < 4; ++t) {
    int i = idx + t;
    int m = i >> 14, r = i & 16383;
    int n = r >> 7, k = r & 127;
    const float* srcm;
    bool kperm;
    if (m == 0)      { srcm = ipw; kperm = false; }
    else if (m <= 3) { srcm = gw  + (size_t)(m - 1) * 16384; kperm = true; }
    else if (m <= 6) { srcm = gew + (size_t)(m - 4) * 16384; kperm = false; }
    else             { srcm = opw; kperm = true; }
    int kk = kperm ? ((k & 7) * 16 + (k >> 3)) : k;
    wt[i] = f2bf(srcm[kk * HID + n]);
  }
}

// Permute per-layer param vectors: out[i][p] = in[i][c(p)].
__global__ void prep_params_kernel(const float* __restrict__ gb,
                                   const float* __restrict__ lns,
                                   const float* __restrict__ lnb,
                                   float* __restrict__ bp,
                                   float* __restrict__ lsp,
                                   float* __restrict__ lbp)
{
  int idx = threadIdx.x + blockIdx.x * 128;  // 0..383
  if (idx < 384) {
    int i = idx >> 7, p = idx & 127;
    int c = (p & 7) * 16 + (p >> 3);
    bp[idx]  = gb[i * 128 + c];
    lsp[idx] = lns[i * 128 + c];
    lbp[idx] = lnb[i * 128 + c];
  }
}

// ---------------------------------------------------------------------------
// LN, natural variant (fallback): natural agg/res/params; permuted xb.
// ---------------------------------------------------------------------------
__global__ __launch_bounds__(256) void ln_nat_kernel(
    const float* __restrict__ agg, const float* __restrict__ b,
    const float* res, const float* __restrict__ lnS,
    const float* __restrict__ lnB, float* xf, unsigned short* __restrict__ xb,
    int n)
{
  const int wave = threadIdx.x >> 6;
  const int lane = threadIdx.x & 63;
  const long node = (long)blockIdx.x * 4 + wave;
  if (node >= n) return;

  float2 v = *(const float2*)&agg[node * HID + lane * 2];
  float2 bb = *(const float2*)&b[lane * 2];
  v.x += bb.x; v.y += bb.y;
  v.x = fmaxf(v.x, 0.f); v.y = fmaxf(v.y, 0.f);
  if (res != nullptr) {
    float2 rr = *(const float2*)&res[node * HID + lane * 2];
    v.x += rr.x; v.y += rr.y;
  }
  float s = v.x + v.y;
  #pragma unroll
  for (int off = 32; off >= 1; off >>= 1) s += __shfl_xor(s, off);
  float mean = s * (1.f / 128.f);
  float dx = v.x - mean, dy = v.y - mean;
  float q = dx * dx + dy * dy;
  #pragma unroll
  for (int off = 32; off >= 1; off >>= 1) q += __shfl_xor(q, off);
  float rstd = rsqrtf(q * (1.f / 128.f) + 1e-5f);
  float2 sc = *(const float2*)&lnS[lane * 2];
  float2 sb = *(const float2*)&lnB[lane * 2];
  float ox = dx * rstd * sc.x + sb.x;
  float oy = dy * rstd * sc.y + sb.y;
  *(float2*)&xf[node * HID + lane * 2] = make_float2(ox, oy);
  int c0 = lane * 2, c1 = lane * 2 + 1;
  xb[node * HID + ((c0 & 15) * 8 + (c0 >> 4))] = f2bf(ox);
  xb[node * HID + ((c1 & 15) * 8 + (c1 >> 4))] = f2bf(oy);
}

// ---------------------------------------------------------------------------
// Pooling (natural layout; out_proj writes natural fp32).
// ---------------------------------------------------------------------------
__global__ void graph_count_kernel(const int* __restrict__ batch, int n,
                                   int nG, int* __restrict__ counts)
{
  int g = threadIdx.x;
  if (g >= nG) return;
  int lo0 = 0, hi0 = n;
  while (lo0 < hi0) { int mid = (lo0 + hi0) >> 1; if (batch[mid] < g) lo0 = mid + 1; else hi0 = mid; }
  int lo1 = lo0, hi1 = n;
  while (lo1 < hi1) { int mid = (lo1 + hi1) >> 1; if (batch[mid] < g + 1) lo1 = mid + 1; else hi1 = mid; }
  counts[g] = lo1 - lo0;
}

__global__ __launch_bounds__(128) void pool_kernel(
    const float* __restrict__ X, const int* __restrict__ batch, int n,
    float* __restrict__ sums)
{
  const int col = threadIdx.x;
  long n0 = (long)blockIdx.x * 64;
  long n1 = n0 + 64; if (n1 > n) n1 = n;
  if (n0 >= n) return;
  float s = 0.f;
  int g = batch[n0];
  for (long i = n0; i < n1; ++i) {
    int gi = batch[i];
    if (gi != g) {
      atomicAdd(&sums[g * HID + col], s);
      s = 0.f;
      g = gi;
    }
    s += X[i * HID + col];
  }
  atomicAdd(&sums[g * HID + col], s);
}

__global__ void finalize_kernel(const float* __restrict__ sums,
                                const int* __restrict__ counts,
                                float* __restrict__ out, int total)
{
  int i = blockIdx.x * 256 + threadIdx.x;
  if (i < total) {
    int g = i >> 7;
    float c = (float)counts[g];
    out[i] = sums[i] / fmaxf(c, 1.f);
  }
}

// ---------------------------------------------------------------------------
extern "C" void kernel_launch(void* const* d_in, const int* in_sizes, int n_in,
                              void* d_out, int out_size, void* d_ws, size_t ws_size,
                              hipStream_t stream)
{
  const float* nf    = (const float*)d_in[0];
  const float* ea    = (const float*)d_in[1];
  const float* ipw   = (const float*)d_in[2];
  const float* ipb   = (const float*)d_in[3];
  const float* gw    = (const float*)d_in[4];
  const float* gew   = (const float*)d_in[5];
  const float* gb    = (const float*)d_in[6];
  const float* lns   = (const float*)d_in[7];
  const float* lnb   = (const float*)d_in[8];
  const float* opw   = (const float*)d_in[9];
  const float* opb   = (const float*)d_in[10];
  const int*   ei    = (const int*)d_in[11];
  const int*   batch = (const int*)d_in[12];
  float* out = (float*)d_out;

  const int N = 100000;
  const int E = 800000;
  const int G = 64;
  const int* srcI = ei;
  const int* dstI = ei + E;

  char* ws = (char*)d_ws;
  const size_t nodeF = (size_t)N * HID * sizeof(float);          // 51.2 MB
  const size_t nodeB = (size_t)N * HID * sizeof(unsigned short); // 25.6 MB
  size_t off = 0;
  float*          xf   = (float*)(ws + off); off += nodeF;       // residual (perm)
  float*          agg  = (float*)(ws + off); off += nodeF;       // out_proj out / fb agg
  unsigned short* xb   = (unsigned short*)(ws + off); off += nodeB;  // x bf16 (perm)
  unsigned short* hb   = (unsigned short*)(ws + off); off += nodeB;  // h bf16 (perm)
  unsigned short* wt   = (unsigned short*)(ws + off); off += 8 * 16384 * 2;
  float*          bp   = (float*)(ws + off); off += 384 * 4;
  float*          lsp  = (float*)(ws + off); off += 384 * 4;
  float*          lbp  = (float*)(ws + off); off += 384 * 4;
  int*            perm = (int*)(ws + off); off += (size_t)E * 4;
  int*            ssrc = (int*)(ws + off); off += (size_t)E * 4;
  int*            sdst = (int*)(ws + off); off += (size_t)E * 4;
  int*            hist = (int*)(ws + off); off += (size_t)N * 4;
  int*            curs = (int*)(ws + off); off += (size_t)N * 4;
  int*            part = (int*)(ws + off); off += 512 * 4;
  float*          sums = (float*)(ws + off); off += (size_t)G * HID * 4;
  int*            cnts = (int*)(ws + off); off += G * 4;
  unsigned short* eas  = (unsigned short*)(ws + off);
  off += (size_t)E * HID * sizeof(unsigned short);               // 204.8 MB
  unsigned short* msgs = (unsigned short*)(ws + off);
  off += 3 * (size_t)E * HID * sizeof(unsigned short);           // 614.4 MB
  const bool hoisted = (ws_size >= off);

  dim3 blk(256);
  const int nBlkN = (N + 127) / 128;   // 782
  const int nBlkE = E / 128;           // 6250
  const int nBins = (N + 255) / 256;   // 391

  prep_w_kernel<<<128, blk, 0, stream>>>(ipw, gw, gew, opw, wt);
  prep_params_kernel<<<3, dim3(128), 0, stream>>>(gb, lns, lnb, bp, lsp, lbp);

  // counting sort of edges by dst; after scatter, curs[d] = segment end
  hipMemsetAsync(hist, 0, (size_t)N * 4, stream);
  hist_kernel<<<(E + 255) / 256, blk, 0, stream>>>(dstI, E, hist);
  scan1_kernel<<<nBins, blk, 0, stream>>>(hist, N, part);
  scan2_kernel<<<1, dim3(512), 0, stream>>>(part, nBins);
  scan3_kernel<<<nBins, blk, 0, stream>>>(hist, part, curs, N);
  scatter_kernel<<<(E + 255) / 256, blk, 0, stream>>>(srcI, dstI, E, curs,
                                                      perm, ssrc, sdst);

  if (hoisted) {
    // random gather ONCE with max MLP, then pure-streaming tri-GEMM
    gather_ea_kernel<<<(int)(((long)E * 32 + 255) / 256), blk, 0, stream>>>(
        ea, perm, eas, E);
    tri_edge_gemm_kernel<<<nBlkE, blk, 0, stream>>>(
        eas, wt + (size_t)4 * 16384, msgs, E);
  }

  // x0 = bf16(nf @ ipw + ipb)  -> xb (perm)
  gemm_node_kernel<true, true, true><<<nBlkN, blk, 0, stream>>>(
      nf, wt, ipb, nullptr, xb, N);

  for (int i = 0; i < 3; ++i) {
    // h = x @ gcn_w[i] -> hb (bf16, perm)
    gemm_node_kernel<false, false, true><<<nBlkN, blk, 0, stream>>>(
        xb, wt + (size_t)(1 + i) * 16384, nullptr, nullptr, hb, N);
    if (hoisted) {
      // fused: agg-sum + relu + bias + residual + LN -> xf, xb
      seg_ln_kernel<<<N / 32, blk, 0, stream>>>(
          msgs + (size_t)i * E * HID, hb, ssrc, curs,
          bp + i * HID, lsp + i * HID, lbp + i * HID,
          (i > 0) ? xf : nullptr, xf, xb);
    } else {
      hipMemsetAsync(agg, 0, nodeF, stream);
      gemm_edge_fb_kernel<<<nBlkE, blk, 0, stream>>>(
          ea, perm, wt + (size_t)(4 + i) * 16384, hb, ssrc, sdst, agg, E);
      ln_nat_kernel<<<(N + 3) / 4, blk, 0, stream>>>(
          agg, gb + i * HID, (i > 0) ? xf : nullptr, lns + i * HID,
          lnb + i * HID, xf, xb, N);
    }
  }

  // y = x @ out_proj_w + out_proj_b -> agg (natural fp32, reused)
  gemm_node_kernel<false, true, false><<<nBlkN, blk, 0, stream>>>(
      xb, wt + (size_t)7 * 16384, opb, agg, nullptr, N);

  // pooling
  graph_count_kernel<<<1, dim3(64), 0, stream>>>(batch, N, G, cnts);
  hipMemsetAsync(sums, 0, (size_t)G * HID * 4, stream);
  pool_kernel<<<(N + 63) / 64, dim3(128), 0, stream>>>(agg, batch, N, sums);
  finalize_kernel<<<(G * HID + 255) / 256, blk, 0, stream>>>(
      sums, cnts, out, G * HID);
}

// Round 14
// 964.475 us; speedup vs baseline: 1.1181x; 1.1181x over previous
//
#include <hip/hip_runtime.h>

#define HID 128

typedef __attribute__((ext_vector_type(8))) short bf16x8;
typedef __attribute__((ext_vector_type(4))) float f32x4;
typedef __attribute__((ext_vector_type(4))) unsigned short u16x4;

__device__ __forceinline__ unsigned short f2bf(float f) {
  union { float f; unsigned u; } v; v.f = f;
  return (unsigned short)((v.u + 0x7FFFu + ((v.u >> 16) & 1u)) >> 16);
}
__device__ __forceinline__ float bf2f(unsigned short h) {
  union { unsigned u; float f; } v; v.u = ((unsigned)h) << 16; return v.f;
}
__device__ __forceinline__ float bf2f_lo(unsigned u) {
  union { unsigned u; float f; } v; v.u = u << 16; return v.f;
}
__device__ __forceinline__ float bf2f_hi(unsigned u) {
  union { unsigned u; float f; } v; v.u = u & 0xffff0000u; return v.f;
}

// Permuted bf16 layout: storage position p holds natural column
// c(p) = (p&7)*16 + (p>>3). Used for xb/hb/msgs in the hoisted path.
// Residual = xb itself (bf16) — no fp32 residual stream.

// ---------------------------------------------------------------------------
// Register-blocked MFMA GEMM, no LDS. Block=256thr=4 waves; wave = 32 rows.
// ---------------------------------------------------------------------------
template<bool SRCF32, bool BIAS, bool OUTBF16>
__global__ __launch_bounds__(256, 3) void gemm_node_kernel(
    const void* __restrict__ Xv, const unsigned short* __restrict__ Wt,
    const float* __restrict__ bias, float* __restrict__ Yf,
    unsigned short* __restrict__ Yb, int nrows)
{
  const int tid  = threadIdx.x;
  const int lane = tid & 63;
  const int wave = tid >> 6;
  const int lr = lane & 15;
  const int lg = lane >> 4;
  const long row0 = (long)blockIdx.x * 128 + wave * 32;

  bf16x8 A[2][4];
  #pragma unroll
  for (int rt = 0; rt < 2; ++rt) {
    long R = row0 + rt * 16 + lr;
    if (R >= nrows) R = nrows - 1;
    if (SRCF32) {
      const float* xp = (const float*)Xv + R * HID;
      #pragma unroll
      for (int ks = 0; ks < 4; ++ks) {
        float4 lo = *(const float4*)(xp + ks * 32 + lg * 8);
        float4 hi = *(const float4*)(xp + ks * 32 + lg * 8 + 4);
        bf16x8 a;
        a[0] = (short)f2bf(lo.x); a[1] = (short)f2bf(lo.y);
        a[2] = (short)f2bf(lo.z); a[3] = (short)f2bf(lo.w);
        a[4] = (short)f2bf(hi.x); a[5] = (short)f2bf(hi.y);
        a[6] = (short)f2bf(hi.z); a[7] = (short)f2bf(hi.w);
        A[rt][ks] = a;
      }
    } else {
      const unsigned short* xp = (const unsigned short*)Xv + R * HID;
      #pragma unroll
      for (int ks = 0; ks < 4; ++ks)
        A[rt][ks] = *(const bf16x8*)(xp + ks * 32 + lg * 8);
    }
  }

  f32x4 acc[2][8];
  #pragma unroll
  for (int rt = 0; rt < 2; ++rt)
    #pragma unroll
    for (int ct = 0; ct < 8; ++ct)
      acc[rt][ct] = (f32x4){0.f, 0.f, 0.f, 0.f};

  #pragma unroll
  for (int ks = 0; ks < 4; ++ks) {
    bf16x8 Bf[8];
    #pragma unroll
    for (int ct = 0; ct < 8; ++ct)
      Bf[ct] = *(const bf16x8*)(Wt + (ct * 16 + lr) * HID + ks * 32 + lg * 8);
    #pragma unroll
    for (int rt = 0; rt < 2; ++rt)
      #pragma unroll
      for (int ct = 0; ct < 8; ++ct)
        acc[rt][ct] = __builtin_amdgcn_mfma_f32_16x16x32_bf16(
            A[rt][ks], Bf[ct], acc[rt][ct], 0, 0, 0);
  }

  #pragma unroll
  for (int rt = 0; rt < 2; ++rt) {
    #pragma unroll
    for (int r = 0; r < 4; ++r) {
      long e = row0 + rt * 16 + lg * 4 + r;
      if (e < nrows) {
        if (OUTBF16) {
          bf16x8 o;
          #pragma unroll
          for (int ct = 0; ct < 8; ++ct) {
            float v = acc[rt][ct][r];
            if (BIAS) v += bias[ct * 16 + lr];
            o[ct] = (short)f2bf(v);
          }
          *(bf16x8*)(Yb + e * HID + lr * 8) = o;   // permuted, contiguous
        } else {
          #pragma unroll
          for (int ct = 0; ct < 8; ++ct) {
            int col = ct * 16 + lr;
            float v = acc[rt][ct][r];
            if (BIAS) v += bias[col];
            Yf[e * HID + col] = v;                  // natural
          }
        }
      }
    }
  }
}

// ---------------------------------------------------------------------------
// Tri edge GEMM (R10/R11 fused form): A = bf16(EA[perm[slot]]) loaded ONCE
// per block (per-lane random 512B-row gather); then for each of the 3
// gcn_ew weights: B-stream from L2 + 64 MFMA + write msgs_w (bf16, permuted,
// dst-sorted). E % 128 == 0.
// ---------------------------------------------------------------------------
__global__ __launch_bounds__(256, 3) void tri_edge_gemm_kernel(
    const float* __restrict__ EA, const int* __restrict__ perm,
    const unsigned short* __restrict__ Wt,   // 3 matrices, stride 16384
    unsigned short* __restrict__ msgs, int nE)  // 3 buffers, stride nE*HID
{
  const int tid  = threadIdx.x;
  const int lane = tid & 63;
  const int wave = tid >> 6;
  const int lr = lane & 15;
  const int lg = lane >> 4;
  const long row0 = (long)blockIdx.x * 128 + wave * 32;

  bf16x8 A[2][4];
  #pragma unroll
  for (int rt = 0; rt < 2; ++rt) {
    long R = row0 + rt * 16 + lr;
    const float* xp = EA + (long)perm[R] * HID;
    #pragma unroll
    for (int ks = 0; ks < 4; ++ks) {
      float4 lo = *(const float4*)(xp + ks * 32 + lg * 8);
      float4 hi = *(const float4*)(xp + ks * 32 + lg * 8 + 4);
      bf16x8 a;
      a[0] = (short)f2bf(lo.x); a[1] = (short)f2bf(lo.y);
      a[2] = (short)f2bf(lo.z); a[3] = (short)f2bf(lo.w);
      a[4] = (short)f2bf(hi.x); a[5] = (short)f2bf(hi.y);
      a[6] = (short)f2bf(hi.z); a[7] = (short)f2bf(hi.w);
      A[rt][ks] = a;
    }
  }

  #pragma unroll 1
  for (int w = 0; w < 3; ++w) {
    const unsigned short* Wp = Wt + (size_t)w * 16384;
    unsigned short* Mp = msgs + (size_t)w * nE * HID;

    f32x4 acc[2][8];
    #pragma unroll
    for (int rt = 0; rt < 2; ++rt)
      #pragma unroll
      for (int ct = 0; ct < 8; ++ct)
        acc[rt][ct] = (f32x4){0.f, 0.f, 0.f, 0.f};

    #pragma unroll
    for (int ks = 0; ks < 4; ++ks) {
      bf16x8 Bf[8];
      #pragma unroll
      for (int ct = 0; ct < 8; ++ct)
        Bf[ct] = *(const bf16x8*)(Wp + (ct * 16 + lr) * HID + ks * 32 + lg * 8);
      #pragma unroll
      for (int rt = 0; rt < 2; ++rt)
        #pragma unroll
        for (int ct = 0; ct < 8; ++ct)
          acc[rt][ct] = __builtin_amdgcn_mfma_f32_16x16x32_bf16(
              A[rt][ks], Bf[ct], acc[rt][ct], 0, 0, 0);
    }

    #pragma unroll
    for (int rt = 0; rt < 2; ++rt) {
      #pragma unroll
      for (int r = 0; r < 4; ++r) {
        long e = row0 + rt * 16 + lg * 4 + r;
        bf16x8 o;
        #pragma unroll
        for (int ct = 0; ct < 8; ++ct) o[ct] = (short)f2bf(acc[rt][ct][r]);
        *(bf16x8*)(Mp + e * HID + lr * 8) = o;
      }
    }
  }
}

// ---------------------------------------------------------------------------
// Fused segmented-reduce + LN, wave-autonomous: each WAVE owns 8 consecutive
// dsts; lane owns a column PAIR (uint loads of msgs/Hb, 256B/row coalesced);
// dual 2-slot unroll; LN via 64-lane shfl only. Residual read from xb (bf16);
// output written ONLY to xb (bf16). No fp32 residual stream.
// ---------------------------------------------------------------------------
__global__ __launch_bounds__(256) void seg_ln_kernel(
    const unsigned short* __restrict__ msgs, const unsigned short* __restrict__ Hb,
    const int* __restrict__ ssrc, const int* __restrict__ segend,
    const float* __restrict__ b, const float* __restrict__ lnS,
    const float* __restrict__ lnB, int useRes,
    unsigned short* __restrict__ xb)
{
  const int lane = threadIdx.x & 63;
  const int wave = threadIdx.x >> 6;
  const int dbase = blockIdx.x * 32 + wave * 8;
  const int c = lane * 2;              // permuted column pair

  const float2 bb = *(const float2*)&b[c];
  const float2 sc = *(const float2*)&lnS[c];
  const float2 sb = *(const float2*)&lnB[c];

  int p = (dbase == 0) ? 0 : segend[dbase - 1];
  #pragma unroll 1
  for (int j = 0; j < 8; ++j) {
    const long node = dbase + j;
    const int end = segend[node];
    float a00 = 0.f, a01 = 0.f, a10 = 0.f, a11 = 0.f;
    int q = p;
    for (; q + 1 < end; q += 2) {
      int s0 = ssrc[q];
      int s1 = ssrc[q + 1];
      unsigned m0 = *(const unsigned*)(msgs + (long)q * HID + c);
      unsigned h0 = *(const unsigned*)(Hb + (long)s0 * HID + c);
      unsigned m1 = *(const unsigned*)(msgs + (long)(q + 1) * HID + c);
      unsigned h1 = *(const unsigned*)(Hb + (long)s1 * HID + c);
      a00 += bf2f_lo(m0) * bf2f_lo(h0);
      a01 += bf2f_hi(m0) * bf2f_hi(h0);
      a10 += bf2f_lo(m1) * bf2f_lo(h1);
      a11 += bf2f_hi(m1) * bf2f_hi(h1);
    }
    if (q < end) {
      int s = ssrc[q];
      unsigned m = *(const unsigned*)(msgs + (long)q * HID + c);
      unsigned h = *(const unsigned*)(Hb + (long)s * HID + c);
      a00 += bf2f_lo(m) * bf2f_lo(h);
      a01 += bf2f_hi(m) * bf2f_hi(h);
    }
    p = end;

    float v0 = fmaxf(a00 + a10 + bb.x, 0.f);
    float v1 = fmaxf(a01 + a11 + bb.y, 0.f);
    if (useRes) {
      unsigned rr = *(const unsigned*)(xb + node * HID + c);
      v0 += bf2f_lo(rr);
      v1 += bf2f_hi(rr);
    }
    float s = v0 + v1, qq = v0 * v0 + v1 * v1;
    #pragma unroll
    for (int off = 32; off >= 1; off >>= 1) {
      s  += __shfl_xor(s, off);
      qq += __shfl_xor(qq, off);
    }
    float mean = s * (1.f / 128.f);
    float var = qq * (1.f / 128.f) - mean * mean;
    float rstd = rsqrtf(var + 1e-5f);
    float o0 = (v0 - mean) * rstd * sc.x + sb.x;
    float o1 = (v1 - mean) * rstd * sc.y + sb.y;
    unsigned pk = (unsigned)f2bf(o0) | ((unsigned)f2bf(o1) << 16);
    *(unsigned*)&xb[node * HID + c] = pk;
  }
}

// ---------------------------------------------------------------------------
// Fallback fused edge kernel (ws too small): EA[perm] fp32 A-load, atomics
// into NATURAL agg (lane-major contiguous lines), permuted bf16 Hb gather.
// ---------------------------------------------------------------------------
__global__ __launch_bounds__(256, 3) void gemm_edge_fb_kernel(
    const float* __restrict__ EA, const int* __restrict__ perm,
    const unsigned short* __restrict__ Wt, const unsigned short* __restrict__ Hb,
    const int* __restrict__ ssrc, const int* __restrict__ sdst,
    float* __restrict__ agg, int nE)
{
  const int tid  = threadIdx.x;
  const int lane = tid & 63;
  const int wave = tid >> 6;
  const int lr = lane & 15;
  const int lg = lane >> 4;
  const long row0 = (long)blockIdx.x * 128 + wave * 32;

  bf16x8 A[2][4];
  #pragma unroll
  for (int rt = 0; rt < 2; ++rt) {
    long R = row0 + rt * 16 + lr;
    const float* xp = EA + (long)perm[R] * HID;
    #pragma unroll
    for (int ks = 0; ks < 4; ++ks) {
      float4 lo = *(const float4*)(xp + ks * 32 + lg * 8);
      float4 hi = *(const float4*)(xp + ks * 32 + lg * 8 + 4);
      bf16x8 a;
      a[0] = (short)f2bf(lo.x); a[1] = (short)f2bf(lo.y);
      a[2] = (short)f2bf(lo.z); a[3] = (short)f2bf(lo.w);
      a[4] = (short)f2bf(hi.x); a[5] = (short)f2bf(hi.y);
      a[6] = (short)f2bf(hi.z); a[7] = (short)f2bf(hi.w);
      A[rt][ks] = a;
    }
  }

  f32x4 acc[2][8];
  #pragma unroll
  for (int rt = 0; rt < 2; ++rt)
    #pragma unroll
    for (int ct = 0; ct < 8; ++ct)
      acc[rt][ct] = (f32x4){0.f, 0.f, 0.f, 0.f};

  #pragma unroll
  for (int ks = 0; ks < 4; ++ks) {
    bf16x8 Bf[8];
    #pragma unroll
    for (int ct = 0; ct < 8; ++ct)
      Bf[ct] = *(const bf16x8*)(Wt + (ct * 16 + lr) * HID + ks * 32 + lg * 8);
    #pragma unroll
    for (int rt = 0; rt < 2; ++rt)
      #pragma unroll
      for (int ct = 0; ct < 8; ++ct)
        acc[rt][ct] = __builtin_amdgcn_mfma_f32_16x16x32_bf16(
            A[rt][ks], Bf[ct], acc[rt][ct], 0, 0, 0);
  }

  #pragma unroll
  for (int rt = 0; rt < 2; ++rt) {
    const long base = row0 + rt * 16 + lg * 4;
    int4 sv = *(const int4*)(ssrc + base);
    int4 dv = *(const int4*)(sdst + base);
    bf16x8 hv0 = *(const bf16x8*)(Hb + (long)sv.x * HID + lr * 8);
    bf16x8 hv1 = *(const bf16x8*)(Hb + (long)sv.y * HID + lr * 8);
    bf16x8 hv2 = *(const bf16x8*)(Hb + (long)sv.z * HID + lr * 8);
    bf16x8 hv3 = *(const bf16x8*)(Hb + (long)sv.w * HID + lr * 8);

    float am[8];
    #pragma unroll
    for (int ct = 0; ct < 8; ++ct)
      am[ct] = acc[rt][ct][0] * bf2f((unsigned short)hv0[ct]);
    int dprev = dv.x;
    {
      bool same = (dv.y == dprev);
      if (!same) {
        float* ap = agg + (long)dprev * HID + lr;
        #pragma unroll
        for (int ct = 0; ct < 8; ++ct) atomicAdd(ap + ct * 16, am[ct]);
      }
      #pragma unroll
      for (int ct = 0; ct < 8; ++ct) {
        float m = acc[rt][ct][1] * bf2f((unsigned short)hv1[ct]);
        am[ct] = same ? am[ct] + m : m;
      }
      dprev = dv.y;
    }
    {
      bool same = (dv.z == dprev);
      if (!same) {
        float* ap = agg + (long)dprev * HID + lr;
        #pragma unroll
        for (int ct = 0; ct < 8; ++ct) atomicAdd(ap + ct * 16, am[ct]);
      }
      #pragma unroll
      for (int ct = 0; ct < 8; ++ct) {
        float m = acc[rt][ct][2] * bf2f((unsigned short)hv2[ct]);
        am[ct] = same ? am[ct] + m : m;
      }
      dprev = dv.z;
    }
    {
      bool same = (dv.w == dprev);
      if (!same) {
        float* ap = agg + (long)dprev * HID + lr;
        #pragma unroll
        for (int ct = 0; ct < 8; ++ct) atomicAdd(ap + ct * 16, am[ct]);
      }
      #pragma unroll
      for (int ct = 0; ct < 8; ++ct) {
        float m = acc[rt][ct][3] * bf2f((unsigned short)hv3[ct]);
        am[ct] = same ? am[ct] + m : m;
      }
      dprev = dv.w;
    }
    float* ap = agg + (long)dprev * HID + lr;
    #pragma unroll
    for (int ct = 0; ct < 8; ++ct) atomicAdd(ap + ct * 16, am[ct]);
  }
}

// ---------------------------------------------------------------------------
// Counting sort of edges by dst. After scatter, curs[d] = segment END.
// ---------------------------------------------------------------------------
__global__ void hist_kernel(const int* __restrict__ dst, int nE,
                            int* __restrict__ hist)
{
  int i = blockIdx.x * 256 + threadIdx.x;
  if (i < nE) atomicAdd(&hist[dst[i]], 1);
}

__global__ __launch_bounds__(256) void scan1_kernel(
    const int* __restrict__ hist, int n, int* __restrict__ partial)
{
  __shared__ int buf[256];
  int t = threadIdx.x;
  int i = blockIdx.x * 256 + t;
  buf[t] = (i < n) ? hist[i] : 0;
  __syncthreads();
  #pragma unroll
  for (int off = 128; off >= 1; off >>= 1) {
    if (t < off) buf[t] += buf[t + off];
    __syncthreads();
  }
  if (t == 0) partial[blockIdx.x] = buf[0];
}

__global__ __launch_bounds__(512) void scan2_kernel(int* __restrict__ partial,
                                                    int nb)
{
  __shared__ int buf[512];
  int t = threadIdx.x;
  buf[t] = (t < nb) ? partial[t] : 0;
  __syncthreads();
  for (int off = 1; off < 512; off <<= 1) {
    int v = (t >= off) ? buf[t - off] : 0;
    __syncthreads();
    buf[t] += v;
    __syncthreads();
  }
  if (t < nb) partial[t] = (t == 0) ? 0 : buf[t - 1];
}

__global__ __launch_bounds__(256) void scan3_kernel(
    const int* __restrict__ hist, const int* __restrict__ partial,
    int* __restrict__ cursor, int n)
{
  __shared__ int buf[256];
  int t = threadIdx.x;
  int i = blockIdx.x * 256 + t;
  int v = (i < n) ? hist[i] : 0;
  buf[t] = v;
  __syncthreads();
  for (int off = 1; off < 256; off <<= 1) {
    int w = (t >= off) ? buf[t - off] : 0;
    __syncthreads();
    buf[t] += w;
    __syncthreads();
  }
  if (i < n) cursor[i] = partial[blockIdx.x] + buf[t] - v;
}

__global__ void scatter_kernel(const int* __restrict__ src,
                               const int* __restrict__ dst, int nE,
                               int* __restrict__ cursor,
                               int* __restrict__ perm,
                               int* __restrict__ ssrc, int* __restrict__ sdst)
{
  int e = blockIdx.x * 256 + threadIdx.x;
  if (e < nE) {
    int d = dst[e];
    int pos = atomicAdd(&cursor[d], 1);
    perm[pos] = e;
    ssrc[pos] = src[e];
    sdst[pos] = d;
  }
}

// ---------------------------------------------------------------------------
// Weight prep: wt[m][n][k'] = bf16(W_m[key][n]); key = c(k') for matrices
// whose A-input is permuted (gcn_w m=1..3, opw m=7), else k'.
// ---------------------------------------------------------------------------
__global__ __launch_bounds__(256) void prep_w_kernel(
    const float* __restrict__ ipw, const float* __restrict__ gw,
    const float* __restrict__ gew, const float* __restrict__ opw,
    unsigned short* __restrict__ wt)
{
  int idx = blockIdx.x * 1024 + threadIdx.x * 4;
  #pragma unroll
  for (int t = 0; t < 4; ++t) {
    int i = idx + t;
    int m = i >> 14, r = i & 16383;
    int n = r >> 7, k = r & 127;
    const float* srcm;
    bool kperm;
    if (m == 0)      { srcm = ipw; kperm = false; }
    else if (m <= 3) { srcm = gw  + (size_t)(m - 1) * 16384; kperm = true; }
    else if (m <= 6) { srcm = gew + (size_t)(m - 4) * 16384; kperm = false; }
    else             { srcm = opw; kperm = true; }
    int kk = kperm ? ((k & 7) * 16 + (k >> 3)) : k;
    wt[i] = f2bf(srcm[kk * HID + n]);
  }
}

// Permute per-layer param vectors: out[i][p] = in[i][c(p)].
__global__ void prep_params_kernel(const float* __restrict__ gb,
                                   const float* __restrict__ lns,
                                   const float* __restrict__ lnb,
                                   float* __restrict__ bp,
                                   float* __restrict__ lsp,
                                   float* __restrict__ lbp)
{
  int idx = threadIdx.x + blockIdx.x * 128;  // 0..383
  if (idx < 384) {
    int i = idx >> 7, p = idx & 127;
    int c = (p & 7) * 16 + (p >> 3);
    bp[idx]  = gb[i * 128 + c];
    lsp[idx] = lns[i * 128 + c];
    lbp[idx] = lnb[i * 128 + c];
  }
}

// ---------------------------------------------------------------------------
// LN, natural variant (fallback): natural agg/res/params; permuted xb.
// ---------------------------------------------------------------------------
__global__ __launch_bounds__(256) void ln_nat_kernel(
    const float* __restrict__ agg, const float* __restrict__ b,
    const float* res, const float* __restrict__ lnS,
    const float* __restrict__ lnB, float* xf, unsigned short* __restrict__ xb,
    int n)
{
  const int wave = threadIdx.x >> 6;
  const int lane = threadIdx.x & 63;
  const long node = (long)blockIdx.x * 4 + wave;
  if (node >= n) return;

  float2 v = *(const float2*)&agg[node * HID + lane * 2];
  float2 bb = *(const float2*)&b[lane * 2];
  v.x += bb.x; v.y += bb.y;
  v.x = fmaxf(v.x, 0.f); v.y = fmaxf(v.y, 0.f);
  if (res != nullptr) {
    float2 rr = *(const float2*)&res[node * HID + lane * 2];
    v.x += rr.x; v.y += rr.y;
  }
  float s = v.x + v.y;
  #pragma unroll
  for (int off = 32; off >= 1; off >>= 1) s += __shfl_xor(s, off);
  float mean = s * (1.f / 128.f);
  float dx = v.x - mean, dy = v.y - mean;
  float q = dx * dx + dy * dy;
  #pragma unroll
  for (int off = 32; off >= 1; off >>= 1) q += __shfl_xor(q, off);
  float rstd = rsqrtf(q * (1.f / 128.f) + 1e-5f);
  float2 sc = *(const float2*)&lnS[lane * 2];
  float2 sb = *(const float2*)&lnB[lane * 2];
  float ox = dx * rstd * sc.x + sb.x;
  float oy = dy * rstd * sc.y + sb.y;
  *(float2*)&xf[node * HID + lane * 2] = make_float2(ox, oy);
  int c0 = lane * 2, c1 = lane * 2 + 1;
  xb[node * HID + ((c0 & 15) * 8 + (c0 >> 4))] = f2bf(ox);
  xb[node * HID + ((c1 & 15) * 8 + (c1 >> 4))] = f2bf(oy);
}

// ---------------------------------------------------------------------------
// Pooling (natural layout; out_proj writes natural fp32).
// ---------------------------------------------------------------------------
__global__ void graph_count_kernel(const int* __restrict__ batch, int n,
                                   int nG, int* __restrict__ counts)
{
  int g = threadIdx.x;
  if (g >= nG) return;
  int lo0 = 0, hi0 = n;
  while (lo0 < hi0) { int mid = (lo0 + hi0) >> 1; if (batch[mid] < g) lo0 = mid + 1; else hi0 = mid; }
  int lo1 = lo0, hi1 = n;
  while (lo1 < hi1) { int mid = (lo1 + hi1) >> 1; if (batch[mid] < g + 1) lo1 = mid + 1; else hi1 = mid; }
  counts[g] = lo1 - lo0;
}

__global__ __launch_bounds__(128) void pool_kernel(
    const float* __restrict__ X, const int* __restrict__ batch, int n,
    float* __restrict__ sums)
{
  const int col = threadIdx.x;
  long n0 = (long)blockIdx.x * 64;
  long n1 = n0 + 64; if (n1 > n) n1 = n;
  if (n0 >= n) return;
  float s = 0.f;
  int g = batch[n0];
  for (long i = n0; i < n1; ++i) {
    int gi = batch[i];
    if (gi != g) {
      atomicAdd(&sums[g * HID + col], s);
      s = 0.f;
      g = gi;
    }
    s += X[i * HID + col];
  }
  atomicAdd(&sums[g * HID + col], s);
}

__global__ void finalize_kernel(const float* __restrict__ sums,
                                const int* __restrict__ counts,
                                float* __restrict__ out, int total)
{
  int i = blockIdx.x * 256 + threadIdx.x;
  if (i < total) {
    int g = i >> 7;
    float c = (float)counts[g];
    out[i] = sums[i] / fmaxf(c, 1.f);
  }
}

// ---------------------------------------------------------------------------
extern "C" void kernel_launch(void* const* d_in, const int* in_sizes, int n_in,
                              void* d_out, int out_size, void* d_ws, size_t ws_size,
                              hipStream_t stream)
{
  const float* nf    = (const float*)d_in[0];
  const float* ea    = (const float*)d_in[1];
  const float* ipw   = (const float*)d_in[2];
  const float* ipb   = (const float*)d_in[3];
  const float* gw    = (const float*)d_in[4];
  const float* gew   = (const float*)d_in[5];
  const float* gb    = (const float*)d_in[6];
  const float* lns   = (const float*)d_in[7];
  const float* lnb   = (const float*)d_in[8];
  const float* opw   = (const float*)d_in[9];
  const float* opb   = (const float*)d_in[10];
  const int*   ei    = (const int*)d_in[11];
  const int*   batch = (const int*)d_in[12];
  float* out = (float*)d_out;

  const int N = 100000;
  const int E = 800000;
  const int G = 64;
  const int* srcI = ei;
  const int* dstI = ei + E;

  char* ws = (char*)d_ws;
  const size_t nodeF = (size_t)N * HID * sizeof(float);          // 51.2 MB
  const size_t nodeB = (size_t)N * HID * sizeof(unsigned short); // 25.6 MB
  size_t off = 0;
  float*          xf   = (float*)(ws + off); off += nodeF;       // fallback residual
  float*          agg  = (float*)(ws + off); off += nodeF;       // out_proj out / fb agg
  unsigned short* xb   = (unsigned short*)(ws + off); off += nodeB;  // x bf16 (perm)
  unsigned short* hb   = (unsigned short*)(ws + off); off += nodeB;  // h bf16 (perm)
  unsigned short* wt   = (unsigned short*)(ws + off); off += 8 * 16384 * 2;
  float*          bp   = (float*)(ws + off); off += 384 * 4;
  float*          lsp  = (float*)(ws + off); off += 384 * 4;
  float*          lbp  = (float*)(ws + off); off += 384 * 4;
  int*            perm = (int*)(ws + off); off += (size_t)E * 4;
  int*            ssrc = (int*)(ws + off); off += (size_t)E * 4;
  int*            sdst = (int*)(ws + off); off += (size_t)E * 4;
  int*            hist = (int*)(ws + off); off += (size_t)N * 4;
  int*            curs = (int*)(ws + off); off += (size_t)N * 4;
  int*            part = (int*)(ws + off); off += 512 * 4;
  float*          sums = (float*)(ws + off); off += (size_t)G * HID * 4;
  int*            cnts = (int*)(ws + off); off += G * 4;
  unsigned short* msgs = (unsigned short*)(ws + off);
  off += 3 * (size_t)E * HID * sizeof(unsigned short);           // 614.4 MB
  const bool hoisted = (ws_size >= off);

  dim3 blk(256);
  const int nBlkN = (N + 127) / 128;   // 782
  const int nBlkE = E / 128;           // 6250
  const int nBins = (N + 255) / 256;   // 391

  prep_w_kernel<<<128, blk, 0, stream>>>(ipw, gw, gew, opw, wt);
  prep_params_kernel<<<3, dim3(128), 0, stream>>>(gb, lns, lnb, bp, lsp, lbp);

  // counting sort of edges by dst; after scatter, curs[d] = segment end
  hipMemsetAsync(hist, 0, (size_t)N * 4, stream);
  hist_kernel<<<(E + 255) / 256, blk, 0, stream>>>(dstI, E, hist);
  scan1_kernel<<<nBins, blk, 0, stream>>>(hist, N, part);
  scan2_kernel<<<1, dim3(512), 0, stream>>>(part, nBins);
  scan3_kernel<<<nBins, blk, 0, stream>>>(hist, part, curs, N);
  scatter_kernel<<<(E + 255) / 256, blk, 0, stream>>>(srcI, dstI, E, curs,
                                                      perm, ssrc, sdst);

  if (hoisted) {
    // ALL THREE edge GEMMs in one pass (fused per-lane perm gather — R11
    // measured faster than split gather+stream)
    tri_edge_gemm_kernel<<<nBlkE, blk, 0, stream>>>(
        ea, perm, wt + (size_t)4 * 16384, msgs, E);
  }

  // x0 = bf16(nf @ ipw + ipb)  -> xb (perm)
  gemm_node_kernel<true, true, true><<<nBlkN, blk, 0, stream>>>(
      nf, wt, ipb, nullptr, xb, N);

  for (int i = 0; i < 3; ++i) {
    // h = x @ gcn_w[i] -> hb (bf16, perm)
    gemm_node_kernel<false, false, true><<<nBlkN, blk, 0, stream>>>(
        xb, wt + (size_t)(1 + i) * 16384, nullptr, nullptr, hb, N);
    if (hoisted) {
      // fused: agg-sum + relu + bias + residual(from xb) + LN -> xb
      seg_ln_kernel<<<N / 32, blk, 0, stream>>>(
          msgs + (size_t)i * E * HID, hb, ssrc, curs,
          bp + i * HID, lsp + i * HID, lbp + i * HID,
          (i > 0) ? 1 : 0, xb);
    } else {
      hipMemsetAsync(agg, 0, nodeF, stream);
      gemm_edge_fb_kernel<<<nBlkE, blk, 0, stream>>>(
          ea, perm, wt + (size_t)(4 + i) * 16384, hb, ssrc, sdst, agg, E);
      ln_nat_kernel<<<(N + 3) / 4, blk, 0, stream>>>(
          agg, gb + i * HID, (i > 0) ? xf : nullptr, lns + i * HID,
          lnb + i * HID, xf, xb, N);
    }
  }

  // y = x @ out_proj_w + out_proj_b -> agg (natural fp32, reused)
  gemm_node_kernel<false, true, false><<<nBlkN, blk, 0, stream>>>(
      xb, wt + (size_t)7 * 16384, opb, agg, nullptr, N);

  // pooling
  graph_count_kernel<<<1, dim3(64), 0, stream>>>(batch, N, G, cnts);
  hipMemsetAsync(sums, 0, (size_t)G * HID * 4, stream);
  pool_kernel<<<(N + 63) / 64, dim3(128), 0, stream>>>(agg, batch, N, sums);
  finalize_kernel<<<(G * HID + 255) / 256, blk, 0, stream>>>(
      sums, cnts, out, G * HID);
}

// Round 16
// 877.315 us; speedup vs baseline: 1.2291x; 1.0993x over previous
//
#include <hip/hip_runtime.h>

#define HID 128

typedef __attribute__((ext_vector_type(8))) short bf16x8;
typedef __attribute__((ext_vector_type(4))) float f32x4;
typedef __attribute__((ext_vector_type(4))) unsigned short u16x4;

__device__ __forceinline__ unsigned short f2bf(float f) {
  union { float f; unsigned u; } v; v.f = f;
  return (unsigned short)((v.u + 0x7FFFu + ((v.u >> 16) & 1u)) >> 16);
}
__device__ __forceinline__ float bf2f(unsigned short h) {
  union { unsigned u; float f; } v; v.u = ((unsigned)h) << 16; return v.f;
}
__device__ __forceinline__ float bf2f_lo(unsigned u) {
  union { unsigned u; float f; } v; v.u = u << 16; return v.f;
}
__device__ __forceinline__ float bf2f_hi(unsigned u) {
  union { unsigned u; float f; } v; v.u = u & 0xffff0000u; return v.f;
}

// Permuted bf16 layout: storage position p holds natural column
// c(p) = (p&7)*16 + (p>>3). Used for xb/hb/msgs in the hoisted path.
// Residual = xb itself (bf16) — no fp32 residual stream.

// ---------------------------------------------------------------------------
// Register-blocked MFMA GEMM, no LDS. Block=256thr=4 waves; wave = 32 rows.
// ---------------------------------------------------------------------------
template<bool SRCF32, bool BIAS, bool OUTBF16>
__global__ __launch_bounds__(256, 3) void gemm_node_kernel(
    const void* __restrict__ Xv, const unsigned short* __restrict__ Wt,
    const float* __restrict__ bias, float* __restrict__ Yf,
    unsigned short* __restrict__ Yb, int nrows)
{
  const int tid  = threadIdx.x;
  const int lane = tid & 63;
  const int wave = tid >> 6;
  const int lr = lane & 15;
  const int lg = lane >> 4;
  const long row0 = (long)blockIdx.x * 128 + wave * 32;

  bf16x8 A[2][4];
  #pragma unroll
  for (int rt = 0; rt < 2; ++rt) {
    long R = row0 + rt * 16 + lr;
    if (R >= nrows) R = nrows - 1;
    if (SRCF32) {
      const float* xp = (const float*)Xv + R * HID;
      #pragma unroll
      for (int ks = 0; ks < 4; ++ks) {
        float4 lo = *(const float4*)(xp + ks * 32 + lg * 8);
        float4 hi = *(const float4*)(xp + ks * 32 + lg * 8 + 4);
        bf16x8 a;
        a[0] = (short)f2bf(lo.x); a[1] = (short)f2bf(lo.y);
        a[2] = (short)f2bf(lo.z); a[3] = (short)f2bf(lo.w);
        a[4] = (short)f2bf(hi.x); a[5] = (short)f2bf(hi.y);
        a[6] = (short)f2bf(hi.z); a[7] = (short)f2bf(hi.w);
        A[rt][ks] = a;
      }
    } else {
      const unsigned short* xp = (const unsigned short*)Xv + R * HID;
      #pragma unroll
      for (int ks = 0; ks < 4; ++ks)
        A[rt][ks] = *(const bf16x8*)(xp + ks * 32 + lg * 8);
    }
  }

  f32x4 acc[2][8];
  #pragma unroll
  for (int rt = 0; rt < 2; ++rt)
    #pragma unroll
    for (int ct = 0; ct < 8; ++ct)
      acc[rt][ct] = (f32x4){0.f, 0.f, 0.f, 0.f};

  #pragma unroll
  for (int ks = 0; ks < 4; ++ks) {
    bf16x8 Bf[8];
    #pragma unroll
    for (int ct = 0; ct < 8; ++ct)
      Bf[ct] = *(const bf16x8*)(Wt + (ct * 16 + lr) * HID + ks * 32 + lg * 8);
    #pragma unroll
    for (int rt = 0; rt < 2; ++rt)
      #pragma unroll
      for (int ct = 0; ct < 8; ++ct)
        acc[rt][ct] = __builtin_amdgcn_mfma_f32_16x16x32_bf16(
            A[rt][ks], Bf[ct], acc[rt][ct], 0, 0, 0);
  }

  #pragma unroll
  for (int rt = 0; rt < 2; ++rt) {
    #pragma unroll
    for (int r = 0; r < 4; ++r) {
      long e = row0 + rt * 16 + lg * 4 + r;
      if (e < nrows) {
        if (OUTBF16) {
          bf16x8 o;
          #pragma unroll
          for (int ct = 0; ct < 8; ++ct) {
            float v = acc[rt][ct][r];
            if (BIAS) v += bias[ct * 16 + lr];
            o[ct] = (short)f2bf(v);
          }
          *(bf16x8*)(Yb + e * HID + lr * 8) = o;   // permuted, contiguous
        } else {
          #pragma unroll
          for (int ct = 0; ct < 8; ++ct) {
            int col = ct * 16 + lr;
            float v = acc[rt][ct][r];
            if (BIAS) v += bias[col];
            Yf[e * HID + col] = v;                  // natural
          }
        }
      }
    }
  }
}

// ---------------------------------------------------------------------------
// Tri edge GEMM (fused): A = bf16(EA[perm[slot]]) loaded ONCE per block via
// NONTEMPORAL loads (each EA row read exactly once — don't pollute L2);
// for each of the 3 gcn_ew weights: B-stream + 64 MFMA + NONTEMPORAL write
// of msgs_w (written once, read ~ms later — bypass L2). E % 128 == 0.
// ---------------------------------------------------------------------------
__global__ __launch_bounds__(256, 3) void tri_edge_gemm_kernel(
    const float* __restrict__ EA, const int* __restrict__ perm,
    const unsigned short* __restrict__ Wt,   // 3 matrices, stride 16384
    unsigned short* __restrict__ msgs, int nE)  // 3 buffers, stride nE*HID
{
  const int tid  = threadIdx.x;
  const int lane = tid & 63;
  const int wave = tid >> 6;
  const int lr = lane & 15;
  const int lg = lane >> 4;
  const long row0 = (long)blockIdx.x * 128 + wave * 32;

  bf16x8 A[2][4];
  #pragma unroll
  for (int rt = 0; rt < 2; ++rt) {
    long R = row0 + rt * 16 + lr;
    const float* xp = EA + (long)perm[R] * HID;
    #pragma unroll
    for (int ks = 0; ks < 4; ++ks) {
      f32x4 lo = __builtin_nontemporal_load((const f32x4*)(xp + ks * 32 + lg * 8));
      f32x4 hi = __builtin_nontemporal_load((const f32x4*)(xp + ks * 32 + lg * 8 + 4));
      bf16x8 a;
      a[0] = (short)f2bf(lo[0]); a[1] = (short)f2bf(lo[1]);
      a[2] = (short)f2bf(lo[2]); a[3] = (short)f2bf(lo[3]);
      a[4] = (short)f2bf(hi[0]); a[5] = (short)f2bf(hi[1]);
      a[6] = (short)f2bf(hi[2]); a[7] = (short)f2bf(hi[3]);
      A[rt][ks] = a;
    }
  }

  #pragma unroll 1
  for (int w = 0; w < 3; ++w) {
    const unsigned short* Wp = Wt + (size_t)w * 16384;
    unsigned short* Mp = msgs + (size_t)w * nE * HID;

    f32x4 acc[2][8];
    #pragma unroll
    for (int rt = 0; rt < 2; ++rt)
      #pragma unroll
      for (int ct = 0; ct < 8; ++ct)
        acc[rt][ct] = (f32x4){0.f, 0.f, 0.f, 0.f};

    #pragma unroll
    for (int ks = 0; ks < 4; ++ks) {
      bf16x8 Bf[8];
      #pragma unroll
      for (int ct = 0; ct < 8; ++ct)
        Bf[ct] = *(const bf16x8*)(Wp + (ct * 16 + lr) * HID + ks * 32 + lg * 8);
      #pragma unroll
      for (int rt = 0; rt < 2; ++rt)
        #pragma unroll
        for (int ct = 0; ct < 8; ++ct)
          acc[rt][ct] = __builtin_amdgcn_mfma_f32_16x16x32_bf16(
              A[rt][ks], Bf[ct], acc[rt][ct], 0, 0, 0);
    }

    #pragma unroll
    for (int rt = 0; rt < 2; ++rt) {
      #pragma unroll
      for (int r = 0; r < 4; ++r) {
        long e = row0 + rt * 16 + lg * 4 + r;
        bf16x8 o;
        #pragma unroll
        for (int ct = 0; ct < 8; ++ct) o[ct] = (short)f2bf(acc[rt][ct][r]);
        __builtin_nontemporal_store(o, (bf16x8*)(Mp + e * HID + lr * 8));
      }
    }
  }
}

// ---------------------------------------------------------------------------
// Fused segmented-reduce + LN, wave-autonomous: each WAVE owns 8 consecutive
// dsts; lane owns a column PAIR. 4-slot unroll (12 loads in flight) to hide
// latency; msgs loads NONTEMPORAL (read-once), Hb loads cached (reused).
// LN via 64-lane shfl only. Residual from xb; output only to xb (bf16).
// ---------------------------------------------------------------------------
__global__ __launch_bounds__(256) void seg_ln_kernel(
    const unsigned short* __restrict__ msgs, const unsigned short* __restrict__ Hb,
    const int* __restrict__ ssrc, const int* __restrict__ segend,
    const float* __restrict__ b, const float* __restrict__ lnS,
    const float* __restrict__ lnB, int useRes,
    unsigned short* __restrict__ xb)
{
  const int lane = threadIdx.x & 63;
  const int wave = threadIdx.x >> 6;
  const int dbase = blockIdx.x * 32 + wave * 8;
  const int c = lane * 2;              // permuted column pair

  const float2 bb = *(const float2*)&b[c];
  const float2 sc = *(const float2*)&lnS[c];
  const float2 sb = *(const float2*)&lnB[c];

  int p = (dbase == 0) ? 0 : segend[dbase - 1];
  #pragma unroll 1
  for (int j = 0; j < 8; ++j) {
    const long node = dbase + j;
    const int end = segend[node];
    float a00 = 0.f, a01 = 0.f, a10 = 0.f, a11 = 0.f;
    int q = p;
    for (; q + 3 < end; q += 4) {
      int s0 = ssrc[q];
      int s1 = ssrc[q + 1];
      int s2 = ssrc[q + 2];
      int s3 = ssrc[q + 3];
      unsigned m0 = __builtin_nontemporal_load((const unsigned*)(msgs + (long)q * HID + c));
      unsigned m1 = __builtin_nontemporal_load((const unsigned*)(msgs + (long)(q + 1) * HID + c));
      unsigned m2 = __builtin_nontemporal_load((const unsigned*)(msgs + (long)(q + 2) * HID + c));
      unsigned m3 = __builtin_nontemporal_load((const unsigned*)(msgs + (long)(q + 3) * HID + c));
      unsigned h0 = *(const unsigned*)(Hb + (long)s0 * HID + c);
      unsigned h1 = *(const unsigned*)(Hb + (long)s1 * HID + c);
      unsigned h2 = *(const unsigned*)(Hb + (long)s2 * HID + c);
      unsigned h3 = *(const unsigned*)(Hb + (long)s3 * HID + c);
      a00 += bf2f_lo(m0) * bf2f_lo(h0);
      a01 += bf2f_hi(m0) * bf2f_hi(h0);
      a10 += bf2f_lo(m1) * bf2f_lo(h1);
      a11 += bf2f_hi(m1) * bf2f_hi(h1);
      a00 += bf2f_lo(m2) * bf2f_lo(h2);
      a01 += bf2f_hi(m2) * bf2f_hi(h2);
      a10 += bf2f_lo(m3) * bf2f_lo(h3);
      a11 += bf2f_hi(m3) * bf2f_hi(h3);
    }
    for (; q < end; ++q) {
      int s = ssrc[q];
      unsigned m = __builtin_nontemporal_load((const unsigned*)(msgs + (long)q * HID + c));
      unsigned h = *(const unsigned*)(Hb + (long)s * HID + c);
      a00 += bf2f_lo(m) * bf2f_lo(h);
      a01 += bf2f_hi(m) * bf2f_hi(h);
    }
    p = end;

    float v0 = fmaxf(a00 + a10 + bb.x, 0.f);
    float v1 = fmaxf(a01 + a11 + bb.y, 0.f);
    if (useRes) {
      unsigned rr = *(const unsigned*)(xb + node * HID + c);
      v0 += bf2f_lo(rr);
      v1 += bf2f_hi(rr);
    }
    float s = v0 + v1, qq = v0 * v0 + v1 * v1;
    #pragma unroll
    for (int off = 32; off >= 1; off >>= 1) {
      s  += __shfl_xor(s, off);
      qq += __shfl_xor(qq, off);
    }
    float mean = s * (1.f / 128.f);
    float var = qq * (1.f / 128.f) - mean * mean;
    float rstd = rsqrtf(var + 1e-5f);
    float o0 = (v0 - mean) * rstd * sc.x + sb.x;
    float o1 = (v1 - mean) * rstd * sc.y + sb.y;
    unsigned pk = (unsigned)f2bf(o0) | ((unsigned)f2bf(o1) << 16);
    *(unsigned*)&xb[node * HID + c] = pk;
  }
}

// ---------------------------------------------------------------------------
// Fallback fused edge kernel (ws too small): EA[perm] fp32 A-load, atomics
// into NATURAL agg (lane-major contiguous lines), permuted bf16 Hb gather.
// ---------------------------------------------------------------------------
__global__ __launch_bounds__(256, 3) void gemm_edge_fb_kernel(
    const float* __restrict__ EA, const int* __restrict__ perm,
    const unsigned short* __restrict__ Wt, const unsigned short* __restrict__ Hb,
    const int* __restrict__ ssrc, const int* __restrict__ sdst,
    float* __restrict__ agg, int nE)
{
  const int tid  = threadIdx.x;
  const int lane = tid & 63;
  const int wave = tid >> 6;
  const int lr = lane & 15;
  const int lg = lane >> 4;
  const long row0 = (long)blockIdx.x * 128 + wave * 32;

  bf16x8 A[2][4];
  #pragma unroll
  for (int rt = 0; rt < 2; ++rt) {
    long R = row0 + rt * 16 + lr;
    const float* xp = EA + (long)perm[R] * HID;
    #pragma unroll
    for (int ks = 0; ks < 4; ++ks) {
      float4 lo = *(const float4*)(xp + ks * 32 + lg * 8);
      float4 hi = *(const float4*)(xp + ks * 32 + lg * 8 + 4);
      bf16x8 a;
      a[0] = (short)f2bf(lo.x); a[1] = (short)f2bf(lo.y);
      a[2] = (short)f2bf(lo.z); a[3] = (short)f2bf(lo.w);
      a[4] = (short)f2bf(hi.x); a[5] = (short)f2bf(hi.y);
      a[6] = (short)f2bf(hi.z); a[7] = (short)f2bf(hi.w);
      A[rt][ks] = a;
    }
  }

  f32x4 acc[2][8];
  #pragma unroll
  for (int rt = 0; rt < 2; ++rt)
    #pragma unroll
    for (int ct = 0; ct < 8; ++ct)
      acc[rt][ct] = (f32x4){0.f, 0.f, 0.f, 0.f};

  #pragma unroll
  for (int ks = 0; ks < 4; ++ks) {
    bf16x8 Bf[8];
    #pragma unroll
    for (int ct = 0; ct < 8; ++ct)
      Bf[ct] = *(const bf16x8*)(Wt + (ct * 16 + lr) * HID + ks * 32 + lg * 8);
    #pragma unroll
    for (int rt = 0; rt < 2; ++rt)
      #pragma unroll
      for (int ct = 0; ct < 8; ++ct)
        acc[rt][ct] = __builtin_amdgcn_mfma_f32_16x16x32_bf16(
            A[rt][ks], Bf[ct], acc[rt][ct], 0, 0, 0);
  }

  #pragma unroll
  for (int rt = 0; rt < 2; ++rt) {
    const long base = row0 + rt * 16 + lg * 4;
    int4 sv = *(const int4*)(ssrc + base);
    int4 dv = *(const int4*)(sdst + base);
    bf16x8 hv0 = *(const bf16x8*)(Hb + (long)sv.x * HID + lr * 8);
    bf16x8 hv1 = *(const bf16x8*)(Hb + (long)sv.y * HID + lr * 8);
    bf16x8 hv2 = *(const bf16x8*)(Hb + (long)sv.z * HID + lr * 8);
    bf16x8 hv3 = *(const bf16x8*)(Hb + (long)sv.w * HID + lr * 8);

    float am[8];
    #pragma unroll
    for (int ct = 0; ct < 8; ++ct)
      am[ct] = acc[rt][ct][0] * bf2f((unsigned short)hv0[ct]);
    int dprev = dv.x;
    {
      bool same = (dv.y == dprev);
      if (!same) {
        float* ap = agg + (long)dprev * HID + lr;
        #pragma unroll
        for (int ct = 0; ct < 8; ++ct) atomicAdd(ap + ct * 16, am[ct]);
      }
      #pragma unroll
      for (int ct = 0; ct < 8; ++ct) {
        float m = acc[rt][ct][1] * bf2f((unsigned short)hv1[ct]);
        am[ct] = same ? am[ct] + m : m;
      }
      dprev = dv.y;
    }
    {
      bool same = (dv.z == dprev);
      if (!same) {
        float* ap = agg + (long)dprev * HID + lr;
        #pragma unroll
        for (int ct = 0; ct < 8; ++ct) atomicAdd(ap + ct * 16, am[ct]);
      }
      #pragma unroll
      for (int ct = 0; ct < 8; ++ct) {
        float m = acc[rt][ct][2] * bf2f((unsigned short)hv2[ct]);
        am[ct] = same ? am[ct] + m : m;
      }
      dprev = dv.z;
    }
    {
      bool same = (dv.w == dprev);
      if (!same) {
        float* ap = agg + (long)dprev * HID + lr;
        #pragma unroll
        for (int ct = 0; ct < 8; ++ct) atomicAdd(ap + ct * 16, am[ct]);
      }
      #pragma unroll
      for (int ct = 0; ct < 8; ++ct) {
        float m = acc[rt][ct][3] * bf2f((unsigned short)hv3[ct]);
        am[ct] = same ? am[ct] + m : m;
      }
      dprev = dv.w;
    }
    float* ap = agg + (long)dprev * HID + lr;
    #pragma unroll
    for (int ct = 0; ct < 8; ++ct) atomicAdd(ap + ct * 16, am[ct]);
  }
}

// ---------------------------------------------------------------------------
// Counting sort of edges by dst. After scatter, curs[d] = segment END.
// ---------------------------------------------------------------------------
__global__ void hist_kernel(const int* __restrict__ dst, int nE,
                            int* __restrict__ hist)
{
  int i = blockIdx.x * 256 + threadIdx.x;
  if (i < nE) atomicAdd(&hist[dst[i]], 1);
}

__global__ __launch_bounds__(256) void scan1_kernel(
    const int* __restrict__ hist, int n, int* __restrict__ partial)
{
  __shared__ int buf[256];
  int t = threadIdx.x;
  int i = blockIdx.x * 256 + t;
  buf[t] = (i < n) ? hist[i] : 0;
  __syncthreads();
  #pragma unroll
  for (int off = 128; off >= 1; off >>= 1) {
    if (t < off) buf[t] += buf[t + off];
    __syncthreads();
  }
  if (t == 0) partial[blockIdx.x] = buf[0];
}

__global__ __launch_bounds__(512) void scan2_kernel(int* __restrict__ partial,
                                                    int nb)
{
  __shared__ int buf[512];
  int t = threadIdx.x;
  buf[t] = (t < nb) ? partial[t] : 0;
  __syncthreads();
  for (int off = 1; off < 512; off <<= 1) {
    int v = (t >= off) ? buf[t - off] : 0;
    __syncthreads();
    buf[t] += v;
    __syncthreads();
  }
  if (t < nb) partial[t] = (t == 0) ? 0 : buf[t - 1];
}

__global__ __launch_bounds__(256) void scan3_kernel(
    const int* __restrict__ hist, const int* __restrict__ partial,
    int* __restrict__ cursor, int n)
{
  __shared__ int buf[256];
  int t = threadIdx.x;
  int i = blockIdx.x * 256 + t;
  int v = (i < n) ? hist[i] : 0;
  buf[t] = v;
  __syncthreads();
  for (int off = 1; off < 256; off <<= 1) {
    int w = (t >= off) ? buf[t - off] : 0;
    __syncthreads();
    buf[t] += w;
    __syncthreads();
  }
  if (i < n) cursor[i] = partial[blockIdx.x] + buf[t] - v;
}

__global__ void scatter_kernel(const int* __restrict__ src,
                               const int* __restrict__ dst, int nE,
                               int* __restrict__ cursor,
                               int* __restrict__ perm,
                               int* __restrict__ ssrc, int* __restrict__ sdst)
{
  int e = blockIdx.x * 256 + threadIdx.x;
  if (e < nE) {
    int d = dst[e];
    int pos = atomicAdd(&cursor[d], 1);
    perm[pos] = e;
    ssrc[pos] = src[e];
    sdst[pos] = d;
  }
}

// ---------------------------------------------------------------------------
// Weight prep: wt[m][n][k'] = bf16(W_m[key][n]); key = c(k') for matrices
// whose A-input is permuted (gcn_w m=1..3, opw m=7), else k'.
// ---------------------------------------------------------------------------
__global__ __launch_bounds__(256) void prep_w_kernel(
    const float* __restrict__ ipw, const float* __restrict__ gw,
    const float* __restrict__ gew, const float* __restrict__ opw,
    unsigned short* __restrict__ wt)
{
  int idx = blockIdx.x * 1024 + threadIdx.x * 4;
  #pragma unroll
  for (int t = 0; t < 4; ++t) {
    int i = idx + t;
    int m = i >> 14, r = i & 16383;
    int n = r >> 7, k = r & 127;
    const float* srcm;
    bool kperm;
    if (m == 0)      { srcm = ipw; kperm = false; }
    else if (m <= 3) { srcm = gw  + (size_t)(m - 1) * 16384; kperm = true; }
    else if (m <= 6) { srcm = gew + (size_t)(m - 4) * 16384; kperm = false; }
    else             { srcm = opw; kperm = true; }
    int kk = kperm ? ((k & 7) * 16 + (k >> 3)) : k;
    wt[i] = f2bf(srcm[kk * HID + n]);
  }
}

// Permute per-layer param vectors: out[i][p] = in[i][c(p)].
__global__ void prep_params_kernel(const float* __restrict__ gb,
                                   const float* __restrict__ lns,
                                   const float* __restrict__ lnb,
                                   float* __restrict__ bp,
                                   float* __restrict__ lsp,
                                   float* __restrict__ lbp)
{
  int idx = threadIdx.x + blockIdx.x * 128;  // 0..383
  if (idx < 384) {
    int i = idx >> 7, p = idx & 127;
    int c = (p & 7) * 16 + (p >> 3);
    bp[idx]  = gb[i * 128 + c];
    lsp[idx] = lns[i * 128 + c];
    lbp[idx] = lnb[i * 128 + c];
  }
}

// ---------------------------------------------------------------------------
// LN, natural variant (fallback): natural agg/res/params; permuted xb.
// ---------------------------------------------------------------------------
__global__ __launch_bounds__(256) void ln_nat_kernel(
    const float* __restrict__ agg, const float* __restrict__ b,
    const float* res, const float* __restrict__ lnS,
    const float* __restrict__ lnB, float* xf, unsigned short* __restrict__ xb,
    int n)
{
  const int wave = threadIdx.x >> 6;
  const int lane = threadIdx.x & 63;
  const long node = (long)blockIdx.x * 4 + wave;
  if (node >= n) return;

  float2 v = *(const float2*)&agg[node * HID + lane * 2];
  float2 bb = *(const float2*)&b[lane * 2];
  v.x += bb.x; v.y += bb.y;
  v.x = fmaxf(v.x, 0.f); v.y = fmaxf(v.y, 0.f);
  if (res != nullptr) {
    float2 rr = *(const float2*)&res[node * HID + lane * 2];
    v.x += rr.x; v.y += rr.y;
  }
  float s = v.x + v.y;
  #pragma unroll
  for (int off = 32; off >= 1; off >>= 1) s += __shfl_xor(s, off);
  float mean = s * (1.f / 128.f);
  float dx = v.x - mean, dy = v.y - mean;
  float q = dx * dx + dy * dy;
  #pragma unroll
  for (int off = 32; off >= 1; off >>= 1) q += __shfl_xor(q, off);
  float rstd = rsqrtf(q * (1.f / 128.f) + 1e-5f);
  float2 sc = *(const float2*)&lnS[lane * 2];
  float2 sb = *(const float2*)&lnB[lane * 2];
  float ox = dx * rstd * sc.x + sb.x;
  float oy = dy * rstd * sc.y + sb.y;
  *(float2*)&xf[node * HID + lane * 2] = make_float2(ox, oy);
  int c0 = lane * 2, c1 = lane * 2 + 1;
  xb[node * HID + ((c0 & 15) * 8 + (c0 >> 4))] = f2bf(ox);
  xb[node * HID + ((c1 & 15) * 8 + (c1 >> 4))] = f2bf(oy);
}

// ---------------------------------------------------------------------------
// Pooling (natural layout; out_proj writes natural fp32).
// ---------------------------------------------------------------------------
__global__ void graph_count_kernel(const int* __restrict__ batch, int n,
                                   int nG, int* __restrict__ counts)
{
  int g = threadIdx.x;
  if (g >= nG) return;
  int lo0 = 0, hi0 = n;
  while (lo0 < hi0) { int mid = (lo0 + hi0) >> 1; if (batch[mid] < g) lo0 = mid + 1; else hi0 = mid; }
  int lo1 = lo0, hi1 = n;
  while (lo1 < hi1) { int mid = (lo1 + hi1) >> 1; if (batch[mid] < g + 1) lo1 = mid + 1; else hi1 = mid; }
  counts[g] = lo1 - lo0;
}

__global__ __launch_bounds__(128) void pool_kernel(
    const float* __restrict__ X, const int* __restrict__ batch, int n,
    float* __restrict__ sums)
{
  const int col = threadIdx.x;
  long n0 = (long)blockIdx.x * 64;
  long n1 = n0 + 64; if (n1 > n) n1 = n;
  if (n0 >= n) return;
  float s = 0.f;
  int g = batch[n0];
  for (long i = n0; i < n1; ++i) {
    int gi = batch[i];
    if (gi != g) {
      atomicAdd(&sums[g * HID + col], s);
      s = 0.f;
      g = gi;
    }
    s += X[i * HID + col];
  }
  atomicAdd(&sums[g * HID + col], s);
}

__global__ void finalize_kernel(const float* __restrict__ sums,
                                const int* __restrict__ counts,
                                float* __restrict__ out, int total)
{
  int i = blockIdx.x * 256 + threadIdx.x;
  if (i < total) {
    int g = i >> 7;
    float c = (float)counts[g];
    out[i] = sums[i] / fmaxf(c, 1.f);
  }
}

// ---------------------------------------------------------------------------
extern "C" void kernel_launch(void* const* d_in, const int* in_sizes, int n_in,
                              void* d_out, int out_size, void* d_ws, size_t ws_size,
                              hipStream_t stream)
{
  const float* nf    = (const float*)d_in[0];
  const float* ea    = (const float*)d_in[1];
  const float* ipw   = (const float*)d_in[2];
  const float* ipb   = (const float*)d_in[3];
  const float* gw    = (const float*)d_in[4];
  const float* gew   = (const float*)d_in[5];
  const float* gb    = (const float*)d_in[6];
  const float* lns   = (const float*)d_in[7];
  const float* lnb   = (const float*)d_in[8];
  const float* opw   = (const float*)d_in[9];
  const float* opb   = (const float*)d_in[10];
  const int*   ei    = (const int*)d_in[11];
  const int*   batch = (const int*)d_in[12];
  float* out = (float*)d_out;

  const int N = 100000;
  const int E = 800000;
  const int G = 64;
  const int* srcI = ei;
  const int* dstI = ei + E;

  char* ws = (char*)d_ws;
  const size_t nodeF = (size_t)N * HID * sizeof(float);          // 51.2 MB
  const size_t nodeB = (size_t)N * HID * sizeof(unsigned short); // 25.6 MB
  size_t off = 0;
  float*          xf   = (float*)(ws + off); off += nodeF;       // fallback residual
  float*          agg  = (float*)(ws + off); off += nodeF;       // out_proj out / fb agg
  unsigned short* xb   = (unsigned short*)(ws + off); off += nodeB;  // x bf16 (perm)
  unsigned short* hb   = (unsigned short*)(ws + off); off += nodeB;  // h bf16 (perm)
  unsigned short* wt   = (unsigned short*)(ws + off); off += 8 * 16384 * 2;
  float*          bp   = (float*)(ws + off); off += 384 * 4;
  float*          lsp  = (float*)(ws + off); off += 384 * 4;
  float*          lbp  = (float*)(ws + off); off += 384 * 4;
  int*            perm = (int*)(ws + off); off += (size_t)E * 4;
  int*            ssrc = (int*)(ws + off); off += (size_t)E * 4;
  int*            sdst = (int*)(ws + off); off += (size_t)E * 4;
  int*            hist = (int*)(ws + off); off += (size_t)N * 4;
  int*            curs = (int*)(ws + off); off += (size_t)N * 4;
  int*            part = (int*)(ws + off); off += 512 * 4;
  float*          sums = (float*)(ws + off); off += (size_t)G * HID * 4;
  int*            cnts = (int*)(ws + off); off += G * 4;
  unsigned short* msgs = (unsigned short*)(ws + off);
  off += 3 * (size_t)E * HID * sizeof(unsigned short);           // 614.4 MB
  const bool hoisted = (ws_size >= off);

  dim3 blk(256);
  const int nBlkN = (N + 127) / 128;   // 782
  const int nBlkE = E / 128;           // 6250
  const int nBins = (N + 255) / 256;   // 391

  prep_w_kernel<<<128, blk, 0, stream>>>(ipw, gw, gew, opw, wt);
  prep_params_kernel<<<3, dim3(128), 0, stream>>>(gb, lns, lnb, bp, lsp, lbp);

  // counting sort of edges by dst; after scatter, curs[d] = segment end
  hipMemsetAsync(hist, 0, (size_t)N * 4, stream);
  hist_kernel<<<(E + 255) / 256, blk, 0, stream>>>(dstI, E, hist);
  scan1_kernel<<<nBins, blk, 0, stream>>>(hist, N, part);
  scan2_kernel<<<1, dim3(512), 0, stream>>>(part, nBins);
  scan3_kernel<<<nBins, blk, 0, stream>>>(hist, part, curs, N);
  scatter_kernel<<<(E + 255) / 256, blk, 0, stream>>>(srcI, dstI, E, curs,
                                                      perm, ssrc, sdst);

  if (hoisted) {
    // ALL THREE edge GEMMs in one pass (fused per-lane perm gather)
    tri_edge_gemm_kernel<<<nBlkE, blk, 0, stream>>>(
        ea, perm, wt + (size_t)4 * 16384, msgs, E);
  }

  // x0 = bf16(nf @ ipw + ipb)  -> xb (perm)
  gemm_node_kernel<true, true, true><<<nBlkN, blk, 0, stream>>>(
      nf, wt, ipb, nullptr, xb, N);

  for (int i = 0; i < 3; ++i) {
    // h = x @ gcn_w[i] -> hb (bf16, perm)
    gemm_node_kernel<false, false, true><<<nBlkN, blk, 0, stream>>>(
        xb, wt + (size_t)(1 + i) * 16384, nullptr, nullptr, hb, N);
    if (hoisted) {
      // fused: agg-sum + relu + bias + residual(from xb) + LN -> xb
      seg_ln_kernel<<<N / 32, blk, 0, stream>>>(
          msgs + (size_t)i * E * HID, hb, ssrc, curs,
          bp + i * HID, lsp + i * HID, lbp + i * HID,
          (i > 0) ? 1 : 0, xb);
    } else {
      hipMemsetAsync(agg, 0, nodeF, stream);
      gemm_edge_fb_kernel<<<nBlkE, blk, 0, stream>>>(
          ea, perm, wt + (size_t)(4 + i) * 16384, hb, ssrc, sdst, agg, E);
      ln_nat_kernel<<<(N + 3) / 4, blk, 0, stream>>>(
          agg, gb + i * HID, (i > 0) ? xf : nullptr, lns + i * HID,
          lnb + i * HID, xf, xb, N);
    }
  }

  // y = x @ out_proj_w + out_proj_b -> agg (natural fp32, reused)
  gemm_node_kernel<false, true, false><<<nBlkN, blk, 0, stream>>>(
      xb, wt + (size_t)7 * 16384, opb, agg, nullptr, N);

  // pooling
  graph_count_kernel<<<1, dim3(64), 0, stream>>>(batch, N, G, cnts);
  hipMemsetAsync(sums, 0, (size_t)G * HID * 4, stream);
  pool_kernel<<<(N + 63) / 64, dim3(128), 0, stream>>>(agg, batch, N, sums);
  finalize_kernel<<<(G * HID + 255) / 256, blk, 0, stream>>>(
      sums, cnts, out, G * HID);
}